// Round 1
// baseline (19971.481 us; speedup 1.0000x reference)
//
#include <hip/hip_runtime.h>

// ============================================================================
// 2-layer LSTM (B=64,T=512,I=256,H=1024) + head, persistent-kernel design.
//
//  prep_kernel : permute+convert weights to fp16 "cat" layout
//                W0cat[4096][1280] = [Wih0 | Whh0], W1cat[4096][2048] = [Wih1 | Whh1]
//                rows permuted so WG wgl owns rows [wgl*32, wgl*32+32) =
//                4 gates x 8 hidden units (hidden slice [wgl*8, wgl*8+8)).
//                Also zeroes h-state broadcast buffers + barrier counters.
//  lstm_kernel : persistent, 256 WGs x 256 thr, 513 stages, custom grid barrier.
//                WG 0..127 = layer0 (t=s), WG 128..255 = layer1 (t=s-1), pipelined.
//                Per WG: gates[64 x 32cols], fp16 MFMA 16x16x32, waves split
//                2-way batch (mh) x 2-way K (kg); A staged global->LDS in 64-k
//                chunks (double buffered); B (weights) streamed from L2/LLC.
//                c-state fp32 in LDS (owner-local); h broadcast fp16 via
//                double-buffered global buffers; __threadfence release/acquire
//                around a 2-level atomic tree barrier for cross-XCD coherence.
//                LDS padded to 84.6 KB -> max 1 WG/CU -> all 256 WGs resident
//                on distinct CUs (barrier deadlock-free by construction).
//  head_kernel : out[64][24] = h2_last @ W_head^T + b_head, fp32.
//
// Workspace (assumes ws_size >= ~27.8 MB):
//   0         W0cat fp16  10,485,760 B
//   10485760  W1cat fp16  16,777,216 B
//   27262976  h0buf fp16 [2][64][1024]  262,144 B   (layer0 h state / layer1 input)
//   27525120  h2buf fp16 [2][64][1024]  262,144 B   (layer1 h state)
//   27787264  sync  uint[256]           1,024 B     (tree barrier)
// ============================================================================

typedef _Float16 h8  __attribute__((ext_vector_type(8)));
typedef _Float16 h2v __attribute__((ext_vector_type(2)));
typedef float    f4  __attribute__((ext_vector_type(4)));

#define WS_W0CAT 0
#define WS_W1CAT 10485760
#define WS_H0    27262976
#define WS_H2    27525120
#define WS_SYNC  27787264

__device__ __forceinline__ h8 cvt8(f4 a, f4 b) {
  h8 r;
  r[0] = (_Float16)a[0]; r[1] = (_Float16)a[1];
  r[2] = (_Float16)a[2]; r[3] = (_Float16)a[3];
  r[4] = (_Float16)b[0]; r[5] = (_Float16)b[1];
  r[6] = (_Float16)b[2]; r[7] = (_Float16)b[3];
  return r;
}

// ---------------------------------------------------------------------------
__global__ void prep_kernel(const float* __restrict__ Wih0, const float* __restrict__ Whh0,
                            const float* __restrict__ Wih1, const float* __restrict__ Whh1,
                            _Float16* __restrict__ W0cat, _Float16* __restrict__ W1cat,
                            unsigned* __restrict__ hz, unsigned* __restrict__ sync_ws)
{
  for (int R = blockIdx.x; R < 4096; R += gridDim.x) {
    const int cc = R & 31, wgl = R >> 5;
    const int src = ((cc >> 3) << 10) + wgl * 8 + (cc & 7);   // gate*1024 + hidden
    const float* s0a = Wih0 + (long)src * 256;
    const float* s0b = Whh0 + (long)src * 1024;
    _Float16* d0 = W0cat + (long)R * 1280;
    for (int k = threadIdx.x; k < 1280; k += blockDim.x)
      d0[k] = (_Float16)((k < 256) ? s0a[k] : s0b[k - 256]);
    const float* s1a = Wih1 + (long)src * 1024;
    const float* s1b = Whh1 + (long)src * 1024;
    _Float16* d1 = W1cat + (long)R * 2048;
    for (int k = threadIdx.x; k < 2048; k += blockDim.x)
      d1[k] = (_Float16)((k < 1024) ? s1a[k] : s1b[k - 1024]);
  }
  const long tid0 = (long)blockIdx.x * blockDim.x + threadIdx.x;
  const long np   = (long)gridDim.x * blockDim.x;
  for (long e = tid0; e < 131072; e += np) hz[e] = 0u;   // h0buf+h2buf = 524288 B
  if (tid0 < 256) sync_ws[tid0] = 0u;
}

// ---------------------------------------------------------------------------
__launch_bounds__(256, 1)
__global__ void lstm_kernel(const float* __restrict__ x,
                            const float* __restrict__ bih0, const float* __restrict__ bhh0,
                            const float* __restrict__ bih1, const float* __restrict__ bhh1,
                            const _Float16* __restrict__ W0cat, const _Float16* __restrict__ W1cat,
                            _Float16* __restrict__ h0buf, _Float16* __restrict__ h2buf,
                            unsigned* __restrict__ sync_ws)
{
  // 55.9 KB static (+28 KB dynamic pad at launch -> 1 WG/CU)
  __shared__ __align__(16) _Float16 Ach[4][2][32 * 72]; // per-wave dbuf A chunks [32 rows][64k +8 pad]
  __shared__ float gbuf[2][64][33];                     // k-split partial gates
  __shared__ float cst[512];                            // c state [64 batch][8 hidden]
  __shared__ float biasl[32];

  const int tid  = threadIdx.x;
  const int wg   = blockIdx.x;
  const int lay  = wg >> 7;        // 0: layer0, 1: layer1
  const int wgl  = wg & 127;       // hidden slice [wgl*8, wgl*8+8)
  const int lane = tid & 63;
  const int wv   = tid >> 6;       // wave 0..3
  const int kg   = wv >> 1;        // K-split half
  const int mh   = wv & 1;         // batch half (32 rows)
  const int quad = lane >> 4;
  const int l15  = lane & 15;

  const int K      = lay ? 2048 : 1280;
  const int nch    = lay ? 16 : 10;        // 64-wide K chunks per kg half
  const int kgbase = kg * (K >> 1);

  const _Float16* Wcat = lay ? W1cat : W0cat;

  if (tid < 32) {
    const int src = ((tid >> 3) << 10) + wgl * 8 + (tid & 7);
    biasl[tid] = lay ? (bih1[src] + bhh1[src]) : (bih0[src] + bhh0[src]);
  }
  for (int i = tid; i < 512; i += 256) cst[i] = 0.f;

  // B-fragment row pointers: lane holds W[col][k], col = wgl*32 + nt*16 + l15
  const _Float16* Wr0 = Wcat + (long)(wgl * 32 + l15) * K + quad * 8;
  const _Float16* Wr1 = Wcat + (long)(wgl * 32 + 16 + l15) * K + quad * 8;

  _Float16* Amine = &Ach[wv][0][0];  // buffers at +0 / +2304 halves
  __syncthreads();

  unsigned epoch = 1;
  for (int s = 0; s <= 512; ++s, ++epoch) {
    const bool active = lay ? (s >= 1) : (s < 512);
    if (active) {
      const int t = lay ? (s - 1) : s;
      const int p = s & 1;
      const _Float16* hA = lay ? (kg ? (h2buf + p * 65536) : (h0buf + p * 65536))
                               : (h0buf + p * 65536);
      _Float16* wr = (lay ? h2buf : h0buf) + ((s + 1) & 1) * 65536;

      f4 acc00 = {0.f,0.f,0.f,0.f}, acc01 = {0.f,0.f,0.f,0.f};
      f4 acc10 = {0.f,0.f,0.f,0.f}, acc11 = {0.f,0.f,0.f,0.f};
      h8 B0[4], B1[4], stg[4];

      auto loadB = [&](int c, h8* Bv) {
        const int k0 = kgbase + c * 64;
        Bv[0] = *(const h8*)(Wr0 + k0);
        Bv[1] = *(const h8*)(Wr1 + k0);
        Bv[2] = *(const h8*)(Wr0 + k0 + 32);
        Bv[3] = *(const h8*)(Wr1 + k0 + 32);
      };
      auto loadA = [&](int c, h8* st) {
        const int k0 = kgbase + c * 64;
        if (!lay && k0 < 256) {          // x is fp32, convert on the fly
          const float* xp = x + (long)(mh * 32) * 131072 + (long)t * 256 + k0;
          #pragma unroll
          for (int i = 0; i < 4; ++i) {
            const int lam = i * 64 + lane;
            const int row = lam >> 3, u = lam & 7;
            const float* q = xp + (long)row * 131072 + u * 8;
            f4 v0 = *(const f4*)q;
            f4 v1 = *(const f4*)(q + 4);
            st[i] = cvt8(v0, v1);
          }
        } else {                          // h buffers, fp16
          const int srck = lay ? (c * 64) : (k0 - 256);
          const _Float16* sp = hA + (mh * 32) * 1024 + srck;
          #pragma unroll
          for (int i = 0; i < 4; ++i) {
            const int lam = i * 64 + lane;
            const int row = lam >> 3, u = lam & 7;
            st[i] = *(const h8*)(sp + row * 1024 + u * 8);
          }
        }
      };
      auto writeA = [&](const h8* st, int buf) {
        _Float16* dp = Amine + buf * 2304;
        #pragma unroll
        for (int i = 0; i < 4; ++i) {
          const int lam = i * 64 + lane;
          const int row = lam >> 3, u = lam & 7;
          *(h8*)(dp + row * 72 + u * 8) = st[i];
        }
      };
      auto consume = [&](int buf, const h8* Bv) {
        const _Float16* ab = Amine + buf * 2304;
        #pragma unroll
        for (int ks = 0; ks < 2; ++ks) {
          const _Float16* ap = ab + ks * 32 + quad * 8;
          h8 a0 = *(const h8*)(ap + l15 * 72);
          h8 a1 = *(const h8*)(ap + (16 + l15) * 72);
          acc00 = __builtin_amdgcn_mfma_f32_16x16x32_f16(a0, Bv[ks*2+0], acc00, 0, 0, 0);
          acc01 = __builtin_amdgcn_mfma_f32_16x16x32_f16(a0, Bv[ks*2+1], acc01, 0, 0, 0);
          acc10 = __builtin_amdgcn_mfma_f32_16x16x32_f16(a1, Bv[ks*2+0], acc10, 0, 0, 0);
          acc11 = __builtin_amdgcn_mfma_f32_16x16x32_f16(a1, Bv[ks*2+1], acc11, 0, 0, 0);
        }
      };

      // software-pipelined chunk loop (dbuf LDS + dbuf B regs)
      loadA(0, stg); loadB(0, B0);
      writeA(stg, 0);
      for (int c = 0; c < nch; c += 2) {
        const bool g1 = (c + 1 < nch);
        const bool g2 = (c + 2 < nch);
        if (g1) { loadA(c + 1, stg); loadB(c + 1, B1); }
        consume(0, B0);
        if (g1) writeA(stg, 1);
        if (g2) { loadA(c + 2, stg); loadB(c + 2, B0); }
        if (g1) consume(1, B1);
        if (g2) writeA(stg, 0);
      }

      // dump k-split partials (D layout: row = quad*4+reg, col = l15)
      {
        const int rb = mh * 32 + quad * 4;
        #pragma unroll
        for (int r = 0; r < 4; ++r) {
          gbuf[kg][rb + r][l15]           = acc00[r];
          gbuf[kg][rb + r][16 + l15]      = acc01[r];
          gbuf[kg][rb + 16 + r][l15]      = acc10[r];
          gbuf[kg][rb + 16 + r][16 + l15] = acc11[r];
        }
      }
      __syncthreads();

      // pointwise LSTM cell: thread -> (batch b, hidden j0,j0+1)
      {
        const int b  = tid >> 2;
        const int j0 = (tid & 3) * 2;
        _Float16 hv[2];
        #pragma unroll
        for (int jj = 0; jj < 2; ++jj) {
          const int j = j0 + jj;
          const float gi = gbuf[0][b][j]      + gbuf[1][b][j]      + biasl[j];
          const float gf = gbuf[0][b][8 + j]  + gbuf[1][b][8 + j]  + biasl[8 + j];
          const float gg = gbuf[0][b][16 + j] + gbuf[1][b][16 + j] + biasl[16 + j];
          const float go = gbuf[0][b][24 + j] + gbuf[1][b][24 + j] + biasl[24 + j];
          const float si = 1.f / (1.f + __expf(-gi));
          const float sf = 1.f / (1.f + __expf(-gf));
          const float so = 1.f / (1.f + __expf(-go));
          const float e2g = __expf(2.f * gg);
          const float tg  = 1.f - 2.f / (e2g + 1.f);      // tanh, inf-safe
          const float cn  = sf * cst[b * 8 + j] + si * tg;
          cst[b * 8 + j] = cn;
          const float e2c = __expf(2.f * cn);
          const float tc  = 1.f - 2.f / (e2c + 1.f);
          hv[jj] = (_Float16)(so * tc);
        }
        h2v hh; hh[0] = hv[0]; hh[1] = hv[1];
        *(h2v*)(wr + b * 1024 + wgl * 8 + j0) = hh;
      }
    } // active

    // ---- grid barrier: release fence -> 2-level atomic tree -> acquire fence
    __syncthreads();
    if (tid == 0) {
      __threadfence();   // release: drain + make h stores agent-visible
      const int g = wg >> 5;  // 8 groups of 32 WGs, counters 64B apart
      unsigned prev = __hip_atomic_fetch_add(&sync_ws[g * 16], 1u,
                        __ATOMIC_ACQ_REL, __HIP_MEMORY_SCOPE_AGENT);
      if (prev == 32u * epoch - 1u) {
        unsigned pr = __hip_atomic_fetch_add(&sync_ws[128], 1u,
                        __ATOMIC_ACQ_REL, __HIP_MEMORY_SCOPE_AGENT);
        if (pr == 8u * epoch - 1u) {
          __hip_atomic_store(&sync_ws[144], epoch,
                             __ATOMIC_RELEASE, __HIP_MEMORY_SCOPE_AGENT);
        } else {
          while (__hip_atomic_load(&sync_ws[144], __ATOMIC_RELAXED,
                                   __HIP_MEMORY_SCOPE_AGENT) < epoch) {}
        }
      } else {
        while (__hip_atomic_load(&sync_ws[144], __ATOMIC_RELAXED,
                                 __HIP_MEMORY_SCOPE_AGENT) < epoch) {}
      }
    }
    __syncthreads();
    __threadfence();     // acquire: invalidate stale L1/L2 before reading new h
  }
}

// ---------------------------------------------------------------------------
__global__ void head_kernel(const _Float16* __restrict__ h2, const float* __restrict__ Wh,
                            const float* __restrict__ bh, float* __restrict__ out)
{
  const int blk = blockIdx.x;            // 64*24 blocks
  const int b = blk / 24, j = blk % 24;
  const int lane = threadIdx.x;          // 64
  const _Float16* hp = h2 + b * 1024;
  const float*    wp = Wh + j * 1024;
  float sum = 0.f;
  #pragma unroll
  for (int k0 = 0; k0 < 1024; k0 += 64)
    sum += (float)hp[k0 + lane] * wp[k0 + lane];
  #pragma unroll
  for (int off = 32; off > 0; off >>= 1)
    sum += __shfl_down(sum, off, 64);
  if (lane == 0) out[b * 24 + j] = sum + bh[j];
}

// ---------------------------------------------------------------------------
extern "C" void kernel_launch(void* const* d_in, const int* in_sizes, int n_in,
                              void* d_out, int out_size, void* d_ws, size_t ws_size,
                              hipStream_t stream)
{
  const float* x    = (const float*)d_in[0];
  const float* Wih0 = (const float*)d_in[1];
  const float* Whh0 = (const float*)d_in[2];
  const float* bih0 = (const float*)d_in[3];
  const float* bhh0 = (const float*)d_in[4];
  const float* Wih1 = (const float*)d_in[5];
  const float* Whh1 = (const float*)d_in[6];
  const float* bih1 = (const float*)d_in[7];
  const float* bhh1 = (const float*)d_in[8];
  const float* Whd  = (const float*)d_in[9];
  const float* bhd  = (const float*)d_in[10];

  char* ws = (char*)d_ws;
  _Float16* W0cat   = (_Float16*)(ws + WS_W0CAT);
  _Float16* W1cat   = (_Float16*)(ws + WS_W1CAT);
  _Float16* h0buf   = (_Float16*)(ws + WS_H0);
  _Float16* h2buf   = (_Float16*)(ws + WS_H2);
  unsigned* sync_ws = (unsigned*)(ws + WS_SYNC);
  float* out = (float*)d_out;

  prep_kernel<<<dim3(1024), dim3(256), 0, stream>>>(
      Wih0, Whh0, Wih1, Whh1, W0cat, W1cat, (unsigned*)(ws + WS_H0), sync_ws);

  // 28672 B dynamic LDS pad -> 84.6 KB/WG -> exactly 1 WG/CU -> all 256 WGs
  // co-resident on 256 CUs; custom grid barrier is deadlock-free.
  lstm_kernel<<<dim3(256), dim3(256), 28672, stream>>>(
      x, bih0, bhh0, bih1, bhh1, W0cat, W1cat, h0buf, h2buf, sync_ws);

  head_kernel<<<dim3(64 * 24), dim3(64), 0, stream>>>(
      h2buf + 65536, Whd, bhd, out);
}

// Round 2
// 11573.384 us; speedup vs baseline: 1.7256x; 1.7256x over previous
//
#include <hip/hip_runtime.h>

// ============================================================================
// 2-layer LSTM (B=64,T=512,I=256,H=1024) + head. Persistent kernel, R2.
//
// R2 changes vs R1 (which was coherence-stall-bound at 38.8 us/stage):
//  * NO per-stage __threadfence / cache maintenance. h crosses XCDs via the
//    coherence point explicitly: stores = relaxed agent atomics (write-through),
//    loads = relaxed agent atomics (L2-bypass). Weights stay L2-resident.
//  * Barrier: relaxed 2-level tree, 8 spread flag lines (32 spinners each),
//    s_sleep backoff. No acq_rel (avoids wbl2/inv per stage).
//  * No LDS A-staging: MFMA fragments loaded straight from global (full-line).
//  * 512 thr/WG, waves = 8-way K-split (kg), no B duplication. A+B fully
//    register-preloaded per stage (B issued first: in-order vmcnt drains B
//    early, A streams). kg partials reduced via transposed LDS gbufT (f4 ops).
//
// Workspace:
//   0         W0cat fp16 [4096][1280]  10,485,760 B
//   10485760  W1cat fp16 [4096][2048]  16,777,216 B
//   27262976  h0buf fp16 [2][64][1024]    262,144 B
//   27525120  h2buf fp16 [2][64][1024]    262,144 B
//   27787264  sync  uint[1536]              6,144 B
// ============================================================================

typedef _Float16 h8 __attribute__((ext_vector_type(8)));
typedef float    f4 __attribute__((ext_vector_type(4)));

#define WS_W0CAT 0
#define WS_W1CAT 10485760
#define WS_H0    27262976
#define WS_H2    27525120
#define WS_SYNC  27787264

static __device__ __forceinline__ float sigm(float v) { return 1.f / (1.f + __expf(-v)); }
static __device__ __forceinline__ float tanh_fast(float v) {
  const float e = __expf(2.f * v);
  return 1.f - 2.f / (e + 1.f);          // inf-safe tanh
}

// ---------------------------------------------------------------------------
__global__ void prep_kernel(const float* __restrict__ Wih0, const float* __restrict__ Whh0,
                            const float* __restrict__ Wih1, const float* __restrict__ Whh1,
                            _Float16* __restrict__ W0cat, _Float16* __restrict__ W1cat,
                            unsigned* __restrict__ hz, unsigned* __restrict__ sync_ws)
{
  for (int R = blockIdx.x; R < 4096; R += gridDim.x) {
    const int cc = R & 31, wgl = R >> 5;
    const int src = ((cc >> 3) << 10) + wgl * 8 + (cc & 7);   // gate*1024 + hidden
    const float* s0a = Wih0 + (long)src * 256;
    const float* s0b = Whh0 + (long)src * 1024;
    _Float16* d0 = W0cat + (long)R * 1280;
    for (int k = threadIdx.x; k < 1280; k += blockDim.x)
      d0[k] = (_Float16)((k < 256) ? s0a[k] : s0b[k - 256]);
    const float* s1a = Wih1 + (long)src * 1024;
    const float* s1b = Whh1 + (long)src * 1024;
    _Float16* d1 = W1cat + (long)R * 2048;
    for (int k = threadIdx.x; k < 2048; k += blockDim.x)
      d1[k] = (_Float16)((k < 1024) ? s1a[k] : s1b[k - 1024]);
  }
  const long tid0 = (long)blockIdx.x * blockDim.x + threadIdx.x;
  const long np   = (long)gridDim.x * blockDim.x;
  for (long e = tid0; e < 131072; e += np) hz[e] = 0u;   // h0buf+h2buf = 524288 B
  if (tid0 < 1536) sync_ws[tid0] = 0u;
}

// ---------------------------------------------------------------------------
// Per-wave GEMM slice: 64 rows x 32 cols x (K/8) for wave kg.
// A fragments loaded directly from global: x (fp32, cached) or h (fp16,
// agent-scope L2-bypass u64 atomic loads). B from L2-resident Wcat.
// Issue order: all B (fast, retire early under in-order vmcnt), then all A.
template<int NKS, bool L0>
static __device__ __forceinline__ void gemm_part(
    const float* __restrict__ xt,        // x + t*256 (row 0), lay0 only
    const _Float16* __restrict__ hsrc,   // h source (row 0), parity-selected
    int hoff,                            // absolute-k offset of h region
    int kgbase,
    const _Float16* __restrict__ Wr0, const _Float16* __restrict__ Wr1,
    int quad, int l15, f4 (&acc)[4][2])
{
  h8 Bf[NKS][2];
  h8 Af[NKS][4];
#pragma unroll
  for (int ks = 0; ks < NKS; ++ks) {
    const int kq = kgbase + ks * 32 + quad * 8;
    Bf[ks][0] = *(const h8*)(Wr0 + kq);
    Bf[ks][1] = *(const h8*)(Wr1 + kq);
  }
#pragma unroll
  for (int ks = 0; ks < NKS; ++ks) {
    const int kabs = kgbase + ks * 32;
    const int kq   = kabs + quad * 8;
    if (L0 && kabs < 256) {              // x region (wave-uniform branch)
      const float* xp = xt + (long)l15 * 131072 + kq;
#pragma unroll
      for (int r = 0; r < 4; ++r) {
        const float* q = xp + (long)r * 16 * 131072;
        const f4 v0 = *(const f4*)q;
        const f4 v1 = *(const f4*)(q + 4);
        h8 t;
        t[0]=(_Float16)v0[0]; t[1]=(_Float16)v0[1]; t[2]=(_Float16)v0[2]; t[3]=(_Float16)v0[3];
        t[4]=(_Float16)v1[0]; t[5]=(_Float16)v1[1]; t[6]=(_Float16)v1[2]; t[7]=(_Float16)v1[3];
        Af[ks][r] = t;
      }
    } else {                             // h region: coherent (L2-bypass) loads
      const int hk = kq - hoff;
#pragma unroll
      for (int r = 0; r < 4; ++r) {
        const unsigned long long* hp =
            (const unsigned long long*)(hsrc + ((long)(r * 16 + l15) * 1024 + hk));
        union { unsigned long long u[2]; h8 v; } cc;
        cc.u[0] = __hip_atomic_load(hp,     __ATOMIC_RELAXED, __HIP_MEMORY_SCOPE_AGENT);
        cc.u[1] = __hip_atomic_load(hp + 1, __ATOMIC_RELAXED, __HIP_MEMORY_SCOPE_AGENT);
        Af[ks][r] = cc.v;
      }
    }
  }
#pragma unroll
  for (int ks = 0; ks < NKS; ++ks) {
#pragma unroll
    for (int r = 0; r < 4; ++r) {
      acc[r][0] = __builtin_amdgcn_mfma_f32_16x16x32_f16(Af[ks][r], Bf[ks][0], acc[r][0], 0, 0, 0);
      acc[r][1] = __builtin_amdgcn_mfma_f32_16x16x32_f16(Af[ks][r], Bf[ks][1], acc[r][1], 0, 0, 0);
    }
  }
}

// ---------------------------------------------------------------------------
__launch_bounds__(512, 1)
__global__ void lstm_kernel(const float* __restrict__ x,
                            const float* __restrict__ bih0, const float* __restrict__ bhh0,
                            const float* __restrict__ bih1, const float* __restrict__ bhh1,
                            const _Float16* __restrict__ W0cat, const _Float16* __restrict__ W1cat,
                            _Float16* __restrict__ h0buf, _Float16* __restrict__ h2buf,
                            unsigned* __restrict__ sync_ws)
{
  extern __shared__ float dynls[];                 // gbufT[8][32][65] = 66,560 B
  float (*gbufT)[32][65] = (float(*)[32][65])dynls;
  __shared__ float cst[512];                       // c state, [jh*64 + b]
  __shared__ float biasl[32];
  __shared__ _Float16 htmp[512];                   // [jh*64 + b]

  const int tid  = threadIdx.x;
  const int wg   = blockIdx.x;
  const int lay  = wg >> 7;        // 0: layer0 (t=s), 1: layer1 (t=s-1)
  const int wgl  = wg & 127;       // hidden slice [wgl*8, wgl*8+8)
  const int lane = tid & 63;
  const int kg   = tid >> 6;       // wave index = K-split 0..7
  const int quad = lane >> 4;
  const int l15  = lane & 15;

  const int K      = lay ? 2048 : 1280;
  const int kgbase = kg * (K >> 3);
  const _Float16* Wcat = lay ? W1cat : W0cat;
  const _Float16* Wr0 = Wcat + (long)(wgl * 32 + l15) * K;        // cols 0-15
  const _Float16* Wr1 = Wcat + (long)(wgl * 32 + 16 + l15) * K;   // cols 16-31

  if (tid < 32) {
    const int src = ((tid >> 3) << 10) + wgl * 8 + (tid & 7);
    biasl[tid] = lay ? (bih1[src] + bhh1[src]) : (bih0[src] + bhh0[src]);
  }
  cst[tid] = 0.f;
  __syncthreads();

  unsigned epoch = 1;
  for (int s = 0; s <= 512; ++s, ++epoch) {
    const bool active = lay ? (s >= 1) : (s < 512);
    if (active) {
      const int p = s & 1;
      _Float16* wr = (lay ? h2buf : h0buf) + ((s + 1) & 1) * 65536;

      f4 acc[4][2] = {};
      if (lay == 0) {
        gemm_part<5, true>(x + (long)s * 256, h0buf + p * 65536, 256,
                           kgbase, Wr0, Wr1, quad, l15, acc);
      } else {
        const _Float16* hsrc = ((kg < 4) ? h0buf : h2buf) + p * 65536;
        gemm_part<8, false>(nullptr, hsrc, (kg < 4) ? 0 : 1024,
                            kgbase, Wr0, Wr1, quad, l15, acc);
      }

      // dump partials transposed: gbufT[kg][col][row], f4 along rows
#pragma unroll
      for (int r = 0; r < 4; ++r)
#pragma unroll
        for (int c = 0; c < 2; ++c)
          *(f4*)&gbufT[kg][c * 16 + l15][r * 16 + quad * 4] = acc[r][c];
      __syncthreads();

      // pointwise LSTM cell: thread (jh=tid>>4, b4=tid&15) -> 4 batches
      if (tid < 128) {
        const int jh = tid >> 4, b4 = tid & 15;
        f4 gs[4];
#pragma unroll
        for (int gate = 0; gate < 4; ++gate) {
          const float bv = biasl[gate * 8 + jh];
          f4 sv = {bv, bv, bv, bv};
#pragma unroll
          for (int g = 0; g < 8; ++g)
            sv += *(const f4*)&gbufT[g][gate * 8 + jh][b4 * 4];
          gs[gate] = sv;
        }
        f4 cold = *(const f4*)&cst[jh * 64 + b4 * 4];
        f4 cnew;
        _Float16 hq[4];
#pragma unroll
        for (int i = 0; i < 4; ++i) {
          const float si = sigm(gs[0][i]);
          const float sf = sigm(gs[1][i]);
          const float tg = tanh_fast(gs[2][i]);
          const float so = sigm(gs[3][i]);
          const float cn = sf * cold[i] + si * tg;
          cnew[i] = cn;
          hq[i] = (_Float16)(so * tanh_fast(cn));
        }
        *(f4*)&cst[jh * 64 + b4 * 4] = cnew;
        _Float16* hd = htmp + jh * 64 + b4 * 4;
        hd[0] = hq[0]; hd[1] = hq[1]; hd[2] = hq[2]; hd[3] = hq[3];
      }
      __syncthreads();

      // publish h: write-through agent-scope stores (visible at LLC when
      // drained by the compiler's pre-s_barrier vmcnt(0))
      if (tid < 64) {
        union { unsigned long long u[2]; _Float16 h[8]; } rr;
#pragma unroll
        for (int jh = 0; jh < 8; ++jh) rr.h[jh] = htmp[jh * 64 + tid];
        unsigned long long* q = (unsigned long long*)(wr + (long)tid * 1024 + wgl * 8);
        __hip_atomic_store(q,     rr.u[0], __ATOMIC_RELAXED, __HIP_MEMORY_SCOPE_AGENT);
        __hip_atomic_store(q + 1, rr.u[1], __ATOMIC_RELAXED, __HIP_MEMORY_SCOPE_AGENT);
      }
    } // active

    // ---- grid barrier: relaxed 2-level tree, 8 flag lines, s_sleep backoff.
    // No fences: all cross-WG data moves via agent-scope (coherence-point) ops.
    __syncthreads();
    if (tid == 0) {
      unsigned* grp = sync_ws + (unsigned)(wg >> 5) * 64;
      const unsigned prev = __hip_atomic_fetch_add(grp, 1u, __ATOMIC_RELAXED,
                                                   __HIP_MEMORY_SCOPE_AGENT);
      if (prev == 32u * epoch - 1u) {
        const unsigned pr = __hip_atomic_fetch_add(sync_ws + 512, 1u, __ATOMIC_RELAXED,
                                                   __HIP_MEMORY_SCOPE_AGENT);
        if (pr == 8u * epoch - 1u) {
#pragma unroll
          for (int f = 0; f < 8; ++f)
            __hip_atomic_store(sync_ws + 1024 + f * 64, epoch, __ATOMIC_RELAXED,
                               __HIP_MEMORY_SCOPE_AGENT);
        }
      }
      while (__hip_atomic_load(sync_ws + 1024 + (wg >> 5) * 64, __ATOMIC_RELAXED,
                               __HIP_MEMORY_SCOPE_AGENT) < epoch)
        __builtin_amdgcn_s_sleep(1);
    }
    __syncthreads();
    asm volatile("" ::: "memory");
  }
}

// ---------------------------------------------------------------------------
__global__ void head_kernel(const _Float16* __restrict__ h2, const float* __restrict__ Wh,
                            const float* __restrict__ bh, float* __restrict__ out)
{
  const int blk = blockIdx.x;            // 64*24 blocks
  const int b = blk / 24, j = blk % 24;
  const int lane = threadIdx.x;          // 64
  const _Float16* hp = h2 + b * 1024;
  const float*    wp = Wh + j * 1024;
  float sum = 0.f;
#pragma unroll
  for (int k0 = 0; k0 < 1024; k0 += 64)
    sum += (float)hp[k0 + lane] * wp[k0 + lane];
#pragma unroll
  for (int off = 32; off > 0; off >>= 1)
    sum += __shfl_down(sum, off, 64);
  if (lane == 0) out[b * 24 + j] = sum + bh[j];
}

// ---------------------------------------------------------------------------
extern "C" void kernel_launch(void* const* d_in, const int* in_sizes, int n_in,
                              void* d_out, int out_size, void* d_ws, size_t ws_size,
                              hipStream_t stream)
{
  const float* x    = (const float*)d_in[0];
  const float* Wih0 = (const float*)d_in[1];
  const float* Whh0 = (const float*)d_in[2];
  const float* bih0 = (const float*)d_in[3];
  const float* bhh0 = (const float*)d_in[4];
  const float* Wih1 = (const float*)d_in[5];
  const float* Whh1 = (const float*)d_in[6];
  const float* bih1 = (const float*)d_in[7];
  const float* bhh1 = (const float*)d_in[8];
  const float* Whd  = (const float*)d_in[9];
  const float* bhd  = (const float*)d_in[10];

  char* ws = (char*)d_ws;
  _Float16* W0cat   = (_Float16*)(ws + WS_W0CAT);
  _Float16* W1cat   = (_Float16*)(ws + WS_W1CAT);
  _Float16* h0buf   = (_Float16*)(ws + WS_H0);
  _Float16* h2buf   = (_Float16*)(ws + WS_H2);
  unsigned* sync_ws = (unsigned*)(ws + WS_SYNC);
  float* out = (float*)d_out;

  prep_kernel<<<dim3(1024), dim3(256), 0, stream>>>(
      Wih0, Whh0, Wih1, Whh1, W0cat, W1cat, (unsigned*)(ws + WS_H0), sync_ws);

  // dynamic LDS 81920 B + ~3.2 KB static -> ~85 KB/WG -> exactly 1 WG/CU:
  // 256 WGs co-resident on 256 CUs, custom grid barrier deadlock-free.
  lstm_kernel<<<dim3(256), dim3(512), 81920, stream>>>(
      x, bih0, bhh0, bih1, bhh1, W0cat, W1cat, h0buf, h2buf, sync_ws);

  head_kernel<<<dim3(64 * 24), dim3(64), 0, stream>>>(
      h2buf + 65536, Whd, bhd, out);
}

// Round 3
// 7539.613 us; speedup vs baseline: 2.6489x; 1.5350x over previous
//
#include <hip/hip_runtime.h>

// ============================================================================
// 2-layer LSTM (B=64,T=512,I=256,H=1024) + head. Persistent kernel, R3.
//
// R3 vs R2 (22.5 us/stage, 94% stall):
//  * DECOUPLED layer groups: WG 0-127 = layer0, WG 128-255 = layer1, each with
//    a private 128-WG tree barrier. h0 crosses via a 4-slot FIFO; sequence
//    flags (= barrier release counters) gate producer overwrite (f1 >= n-2)
//    and consumer read (f0 >= n+2). Layer0 runs ahead, absorbing jitter;
//    total ~= sum of layer1 stage times, not sum of max(256 WGs).
//  * FRAGMENT-PACKED layouts: weights repacked (prep) and h published so every
//    MFMA fragment is lane-contiguous 16 B/lane -> full-line coalesced loads
//    (B: one dwordx4 per frag; A: full-line u64 pairs). ~2x fewer TCC reqs.
//  * Explicit 2-flight register pipeline (4-chunk flights + sched_barrier)
//    -> <=2 exposed load latencies per stage instead of 8.
//
// Workspace (28.06 MB):
//   0         W0pack fp16 [128 wgl][40 c][2 colt][512]   10,485,760 B
//   10485760  W1pack fp16 [128 wgl][64 c][2 colt][512]   16,777,216 B
//   27262976  h0q    fp16 4 slots x [32 c][4 r][512]        524,288 B
//   27787264  h2q    fp16 2 slots x same                    262,144 B
//   28049408  sync   uint[2048]                               8,192 B
// ============================================================================

typedef _Float16 h8 __attribute__((ext_vector_type(8)));
typedef float    f4 __attribute__((ext_vector_type(4)));
typedef unsigned long long u64;

#define WS_W0PACK 0
#define WS_W1PACK 10485760
#define WS_H0Q    27262976
#define WS_H2Q    27787264
#define WS_SYNC   28049408

static __device__ __forceinline__ float sigm(float v) { return 1.f / (1.f + __expf(-v)); }
static __device__ __forceinline__ float tanh_fast(float v) {
  const float e = __expf(2.f * v);
  return 1.f - 2.f / (e + 1.f);
}
static __device__ __forceinline__ unsigned ld_flag(const unsigned* p) {
  return __hip_atomic_load(p, __ATOMIC_RELAXED, __HIP_MEMORY_SCOPE_AGENT);
}

// ---------------------------------------------------------------------------
// Pack layout (per WG wgl, layer L with K = 40|64 chunks of 32 k):
//   elem(c, colt, l15, quad, j) at  wgl*K*32 + c*1024 + colt*512 + (l15*4+quad)*8 + j
//   where col = colt*16+l15 (cc), gate = cc>>3, hid = wgl*8+(cc&7),
//         k = c*32 + quad*8 + j.
// h pack (per 128 KB slot): elem(batch,hid) at
//   (hid>>5)*2048 + (batch>>4)*512 + ((batch&15)*4 + ((hid>>3)&3))*8 + (hid&7)
__global__ void prep_kernel(const float* __restrict__ Wih0, const float* __restrict__ Whh0,
                            const float* __restrict__ Wih1, const float* __restrict__ Whh1,
                            _Float16* __restrict__ W0p, _Float16* __restrict__ W1p,
                            unsigned* __restrict__ hz, unsigned* __restrict__ sync_ws)
{
  for (int wgl = blockIdx.x; wgl < 128; wgl += gridDim.x) {
    unsigned* d0 = (unsigned*)(W0p + (long)wgl * 40960);
    for (int t = threadIdx.x; t < 20480; t += blockDim.x) {
      const int j2 = t & 3, quad = (t >> 2) & 3, l15 = (t >> 4) & 15;
      const int colt = (t >> 8) & 1, c = t >> 9;
      const int cc = colt * 16 + l15;
      const int row = ((cc >> 3) << 10) + wgl * 8 + (cc & 7);
      const int k = c * 32 + quad * 8 + j2 * 2;
      float a, b;
      if (k < 256) { a = Wih0[(long)row * 256 + k];        b = Wih0[(long)row * 256 + k + 1]; }
      else         { a = Whh0[(long)row * 1024 + k - 256]; b = Whh0[(long)row * 1024 + k - 255]; }
      union { unsigned u; _Float16 h[2]; } o;
      o.h[0] = (_Float16)a; o.h[1] = (_Float16)b;
      d0[t] = o.u;
    }
    unsigned* d1 = (unsigned*)(W1p + (long)wgl * 65536);
    for (int t = threadIdx.x; t < 32768; t += blockDim.x) {
      const int j2 = t & 3, quad = (t >> 2) & 3, l15 = (t >> 4) & 15;
      const int colt = (t >> 8) & 1, c = t >> 9;
      const int cc = colt * 16 + l15;
      const int row = ((cc >> 3) << 10) + wgl * 8 + (cc & 7);
      const int k = c * 32 + quad * 8 + j2 * 2;
      float a, b;
      if (k < 1024) { a = Wih1[(long)row * 1024 + k];        b = Wih1[(long)row * 1024 + k + 1]; }
      else          { a = Whh1[(long)row * 1024 + k - 1024]; b = Whh1[(long)row * 1024 + k - 1023]; }
      union { unsigned u; _Float16 h[2]; } o;
      o.h[0] = (_Float16)a; o.h[1] = (_Float16)b;
      d1[t] = o.u;
    }
  }
  const long tid0 = (long)blockIdx.x * blockDim.x + threadIdx.x;
  const long np   = (long)gridDim.x * blockDim.x;
  for (long e = tid0; e < 196608; e += np) hz[e] = 0u;   // h0q + h2q
  if (tid0 < 2048) sync_ws[tid0] = 0u;
}

// ---------------------------------------------------------------------------
// Load one 32-k chunk's fragments for this wave (4 A-frags + 2 B-frags).
template<bool L0>
static __device__ __forceinline__ void load_chunk(
    int c_abs, const float* __restrict__ xt,
    const _Float16* __restrict__ h0s, const _Float16* __restrict__ h2s,
    const _Float16* __restrict__ wpk, int lane, h8 A[4], h8 B[2])
{
  const int l15 = lane & 15, quad = lane >> 4;
  const int lofs = (l15 * 4 + quad) * 8;          // lane's packed elem offset
  const _Float16* bp = wpk + c_abs * 1024 + lofs;
  B[0] = *(const h8*)bp;
  B[1] = *(const h8*)(bp + 512);
  if (L0 && c_abs < 8) {                          // x region (fp32, cached)
    const int kq = c_abs * 32 + quad * 8;
    const float* xp = xt + (long)l15 * 131072 + kq;
#pragma unroll
    for (int r = 0; r < 4; ++r) {
      const float* q = xp + (long)r * 16 * 131072;
      const f4 v0 = *(const f4*)q;
      const f4 v1 = *(const f4*)(q + 4);
      h8 t;
      t[0]=(_Float16)v0[0]; t[1]=(_Float16)v0[1]; t[2]=(_Float16)v0[2]; t[3]=(_Float16)v0[3];
      t[4]=(_Float16)v1[0]; t[5]=(_Float16)v1[1]; t[6]=(_Float16)v1[2]; t[7]=(_Float16)v1[3];
      A[r] = t;
    }
  } else {                                        // packed h, coherent loads
    const _Float16* hb = L0 ? (h0s + (c_abs - 8) * 2048)
                            : ((c_abs < 32) ? (h0s + c_abs * 2048)
                                            : (h2s + (c_abs - 32) * 2048));
    const u64* pp = (const u64*)(hb + lofs);
#pragma unroll
    for (int r = 0; r < 4; ++r) {
      union { u64 u[2]; h8 v; } cc;
      cc.u[0] = __hip_atomic_load(pp + r * 128,     __ATOMIC_RELAXED, __HIP_MEMORY_SCOPE_AGENT);
      cc.u[1] = __hip_atomic_load(pp + r * 128 + 1, __ATOMIC_RELAXED, __HIP_MEMORY_SCOPE_AGENT);
      A[r] = cc.v;
    }
  }
}

static __device__ __forceinline__ void consume_chunk(const h8 A[4], const h8 B[2],
                                                     f4 (&acc)[4][2])
{
#pragma unroll
  for (int r = 0; r < 4; ++r) {
    acc[r][0] = __builtin_amdgcn_mfma_f32_16x16x32_f16(A[r], B[0], acc[r][0], 0, 0, 0);
    acc[r][1] = __builtin_amdgcn_mfma_f32_16x16x32_f16(A[r], B[1], acc[r][1], 0, 0, 0);
  }
}

// ---------------------------------------------------------------------------
__launch_bounds__(512, 1)
__global__ void lstm_kernel(const float* __restrict__ x,
                            const float* __restrict__ bih0, const float* __restrict__ bhh0,
                            const float* __restrict__ bih1, const float* __restrict__ bhh1,
                            const _Float16* __restrict__ W0p, const _Float16* __restrict__ W1p,
                            _Float16* __restrict__ h0q, _Float16* __restrict__ h2q,
                            unsigned* __restrict__ sy)
{
  extern __shared__ float dynls[];                 // gbufT[8][32][65] = 66,560 B
  float (*gbufT)[32][65] = (float(*)[32][65])dynls;
  __shared__ float cst[512];
  __shared__ float biasl[32];
  __shared__ _Float16 htmp[512];

  const int tid  = threadIdx.x;
  const int wg   = blockIdx.x;
  const int lay  = wg >> 7;
  const int wgl  = wg & 127;
  const int lane = tid & 63;
  const int kg   = tid >> 6;
  const int l15  = lane & 15;

  const _Float16* wpk = lay ? (W1p + (long)wgl * 65536) : (W0p + (long)wgl * 40960);

  if (tid < 32) {
    const int src = ((tid >> 3) << 10) + wgl * 8 + (tid & 7);
    biasl[tid] = lay ? (bih1[src] + bhh1[src]) : (bih0[src] + bhh0[src]);
  }
  cst[tid] = 0.f;
  __syncthreads();

  unsigned* const base = sy + (lay ? 576 : 0);
  const unsigned* const xflag = lay ? (sy + 320) : (sy + 896);
  const int sub = wgl >> 5;

  const int iters = lay ? 512 : 513;
  for (int n = 0; n < iters; ++n) {
    // ---- group barrier (top of step n): own-group step n-1 complete +
    //      cross-group admission (L0: f1>=n-2 slot-reuse; L1: f0>=n+2 data-ready)
    __syncthreads();
    if (tid == 0) {
      const unsigned e = (unsigned)n + 1u;
      const unsigned prev = __hip_atomic_fetch_add(base + sub * 64, 1u,
                              __ATOMIC_RELAXED, __HIP_MEMORY_SCOPE_AGENT);
      if (prev == 32u * e - 1u) {
        const unsigned p2 = __hip_atomic_fetch_add(base + 256, 1u,
                              __ATOMIC_RELAXED, __HIP_MEMORY_SCOPE_AGENT);
        if (p2 == 4u * e - 1u) {
          if (lay == 0) {
            while ((int)ld_flag(xflag) < n - 2) __builtin_amdgcn_s_sleep(1);
          } else {
            while (ld_flag(xflag) < (unsigned)(n + 2)) __builtin_amdgcn_s_sleep(1);
          }
#pragma unroll
          for (int i = 0; i < 4; ++i)
            __hip_atomic_store(base + 320 + i * 64, e,
                               __ATOMIC_RELAXED, __HIP_MEMORY_SCOPE_AGENT);
        }
      }
      while (ld_flag(base + 320 + sub * 64) < e) __builtin_amdgcn_s_sleep(1);
    }
    __syncthreads();
    asm volatile("" ::: "memory");
    if (n >= 512) continue;                        // L0 epilogue barrier only

    // ---- compute step n
    const _Float16* h0rd = lay ? (h0q + (n & 3) * 65536)          // h0(n)
                               : (h0q + ((n - 1) & 3) * 65536);   // h0(n-1)
    const _Float16* h2rd = h2q + ((n - 1) & 1) * 65536;           // h2(n-1)
    _Float16* wr = lay ? (h2q + (n & 1) * 65536) : (h0q + (n & 3) * 65536);

    f4 acc[4][2] = {};
    if (lay == 0) {
      const float* xt = x + (long)n * 256;
      const int c0 = kg * 5;
      h8 Aa[3][4], Ba[3][2], Ab[2][4], Bb[2][2];
#pragma unroll
      for (int i = 0; i < 3; ++i) load_chunk<true>(c0 + i, xt, h0rd, nullptr, wpk, lane, Aa[i], Ba[i]);
#pragma unroll
      for (int i = 0; i < 2; ++i) load_chunk<true>(c0 + 3 + i, xt, h0rd, nullptr, wpk, lane, Ab[i], Bb[i]);
      __builtin_amdgcn_sched_barrier(0);
#pragma unroll
      for (int i = 0; i < 3; ++i) consume_chunk(Aa[i], Ba[i], acc);
#pragma unroll
      for (int i = 0; i < 2; ++i) consume_chunk(Ab[i], Bb[i], acc);
    } else {
      const int c0 = kg * 8;
      h8 Aa[4][4], Ba[4][2], Ab[4][4], Bb[4][2];
#pragma unroll
      for (int i = 0; i < 4; ++i) load_chunk<false>(c0 + i, nullptr, h0rd, h2rd, wpk, lane, Aa[i], Ba[i]);
#pragma unroll
      for (int i = 0; i < 4; ++i) load_chunk<false>(c0 + 4 + i, nullptr, h0rd, h2rd, wpk, lane, Ab[i], Bb[i]);
      __builtin_amdgcn_sched_barrier(0);
#pragma unroll
      for (int i = 0; i < 4; ++i) consume_chunk(Aa[i], Ba[i], acc);
#pragma unroll
      for (int i = 0; i < 4; ++i) consume_chunk(Ab[i], Bb[i], acc);
    }

    // dump k-split partials transposed: gbufT[kg][col][row]
    {
      const int quad = lane >> 4;
#pragma unroll
      for (int r = 0; r < 4; ++r)
#pragma unroll
        for (int c = 0; c < 2; ++c)
          *(f4*)&gbufT[kg][c * 16 + l15][r * 16 + quad * 4] = acc[r][c];
    }
    __syncthreads();

    // pointwise LSTM cell
    if (tid < 128) {
      const int jh = tid >> 4, b4 = tid & 15;
      f4 gs[4];
#pragma unroll
      for (int gate = 0; gate < 4; ++gate) {
        const float bv = biasl[gate * 8 + jh];
        f4 sv = {bv, bv, bv, bv};
#pragma unroll
        for (int g = 0; g < 8; ++g)
          sv += *(const f4*)&gbufT[g][gate * 8 + jh][b4 * 4];
        gs[gate] = sv;
      }
      f4 cold = *(const f4*)&cst[jh * 64 + b4 * 4];
      f4 cnew;
      _Float16 hq[4];
#pragma unroll
      for (int i = 0; i < 4; ++i) {
        const float si = sigm(gs[0][i]);
        const float sf = sigm(gs[1][i]);
        const float tg = tanh_fast(gs[2][i]);
        const float so = sigm(gs[3][i]);
        const float cn = sf * cold[i] + si * tg;
        cnew[i] = cn;
        hq[i] = (_Float16)(so * tanh_fast(cn));
      }
      *(f4*)&cst[jh * 64 + b4 * 4] = cnew;
      _Float16* hd = htmp + jh * 64 + b4 * 4;
      hd[0] = hq[0]; hd[1] = hq[1]; hd[2] = hq[2]; hd[3] = hq[3];
    }
    __syncthreads();

    // publish h in A-frag-packed layout: thread b=tid owns 8 hid = 16 B chunk
    if (tid < 64) {
      union { u64 u[2]; _Float16 h[8]; } rr;
#pragma unroll
      for (int jh = 0; jh < 8; ++jh) rr.h[jh] = htmp[jh * 64 + tid];
      u64* q = (u64*)(wr + (wgl >> 2) * 2048 + (tid >> 4) * 512
                         + ((tid & 15) * 4 + (wgl & 3)) * 8);
      __hip_atomic_store(q,     rr.u[0], __ATOMIC_RELAXED, __HIP_MEMORY_SCOPE_AGENT);
      __hip_atomic_store(q + 1, rr.u[1], __ATOMIC_RELAXED, __HIP_MEMORY_SCOPE_AGENT);
    }
  }
}

// ---------------------------------------------------------------------------
__global__ void head_kernel(const _Float16* __restrict__ h2s, const float* __restrict__ Wh,
                            const float* __restrict__ bh, float* __restrict__ out)
{
  const int blk = blockIdx.x;            // 64*24
  const int b = blk / 24, j = blk % 24;
  const int lane = threadIdx.x;          // 64
  float sum = 0.f;
#pragma unroll
  for (int k0 = 0; k0 < 1024; k0 += 64) {
    const int hid = k0 + lane;
    const float hv = (float)h2s[(hid >> 5) * 2048 + (b >> 4) * 512
                                + ((b & 15) * 4 + ((hid >> 3) & 3)) * 8 + (hid & 7)];
    sum += hv * Wh[(long)j * 1024 + hid];
  }
#pragma unroll
  for (int off = 32; off > 0; off >>= 1)
    sum += __shfl_down(sum, off, 64);
  if (lane == 0) out[b * 24 + j] = sum + bh[j];
}

// ---------------------------------------------------------------------------
extern "C" void kernel_launch(void* const* d_in, const int* in_sizes, int n_in,
                              void* d_out, int out_size, void* d_ws, size_t ws_size,
                              hipStream_t stream)
{
  const float* x    = (const float*)d_in[0];
  const float* Wih0 = (const float*)d_in[1];
  const float* Whh0 = (const float*)d_in[2];
  const float* bih0 = (const float*)d_in[3];
  const float* bhh0 = (const float*)d_in[4];
  const float* Wih1 = (const float*)d_in[5];
  const float* Whh1 = (const float*)d_in[6];
  const float* bih1 = (const float*)d_in[7];
  const float* bhh1 = (const float*)d_in[8];
  const float* Whd  = (const float*)d_in[9];
  const float* bhd  = (const float*)d_in[10];

  char* ws = (char*)d_ws;
  _Float16* W0p     = (_Float16*)(ws + WS_W0PACK);
  _Float16* W1p     = (_Float16*)(ws + WS_W1PACK);
  _Float16* h0q     = (_Float16*)(ws + WS_H0Q);
  _Float16* h2q     = (_Float16*)(ws + WS_H2Q);
  unsigned* sync_ws = (unsigned*)(ws + WS_SYNC);
  float* out = (float*)d_out;

  prep_kernel<<<dim3(1024), dim3(256), 0, stream>>>(
      Wih0, Whh0, Wih1, Whh1, W0p, W1p, (unsigned*)(ws + WS_H0Q), sync_ws);

  // static ~3.4 KB + dynamic 81920 B > 160KB/2 -> exactly 1 WG/CU -> all 256
  // WGs co-resident; both group barriers deadlock-free.
  lstm_kernel<<<dim3(256), dim3(512), 81920, stream>>>(
      x, bih0, bhh0, bih1, bhh1, W0p, W1p, h0q, h2q, sync_ws);

  head_kernel<<<dim3(64 * 24), dim3(64), 0, stream>>>(
      h2q + 65536, Whd, bhd, out);   // h2(511), slot 511&1 = 1
}